// Round 3
// baseline (1237.883 us; speedup 1.0000x reference)
//
#include <hip/hip_runtime.h>
#include <hip/hip_cooperative_groups.h>

namespace cg = cooperative_groups;

#define PLANE_RES 1024
#define PLANE_STRIDE (PLANE_RES * PLANE_RES)  // float2 elements per plane
#define NBUCKETS 32768                        // 2^15 morton buckets (5 bits/axis)
#define SCAN_THREADS 1024
#define PER_THREAD (NBUCKETS / SCAN_THREADS)  // 32

// cooperative fused-sort geometry
#define COOP_GRID 1024
#define COOP_BLOCK 256
#define COOP_THREADS (COOP_GRID * COOP_BLOCK)   // 262144
#define POS_PER_THREAD 8                        // covers B = 2097152 exactly
#define BINS_PER_BLOCK (NBUCKETS / COOP_GRID)   // 32

// ---------------- morton key: top 5 bits of each axis's level-3 cell --------
__device__ __forceinline__ unsigned part1by2(unsigned v) {
    v &= 0x3ff;
    v = (v | (v << 16)) & 0x030000FFu;
    v = (v | (v << 8))  & 0x0300F00Fu;
    v = (v | (v << 4))  & 0x030C30C3u;
    v = (v | (v << 2))  & 0x09249249u;
    return v;
}

__device__ __forceinline__ unsigned morton_key(float x, float y, float z) {
    int gx = (int)floorf(x * 1023.0f + 0.5f);
    int gy = (int)floorf(y * 1023.0f + 0.5f);
    int gz = (int)floorf(z * 1023.0f + 0.5f);
    unsigned bx = ((unsigned)gx) >> 5;  // [0,31]
    unsigned by = ((unsigned)gy) >> 5;
    unsigned bz = ((unsigned)gz) >> 5;
    return (part1by2(bx) << 2) | (part1by2(by) << 1) | part1by2(bz);  // 15 bits
}

// ---------------- fused sort: memset + hist + scan + scatter (cooperative) --
// Positions + keys live in registers between the histogram and scatter
// phases: no positions re-read, no re-keying, no single-block-scan idle,
// 3 fewer launches.
__global__ __launch_bounds__(COOP_BLOCK, 4) void sort_coop_kernel(
    const float* __restrict__ positions,
    unsigned* __restrict__ offs,         // [NBUCKETS]
    unsigned* __restrict__ block_sums,   // [COOP_GRID]
    float4* __restrict__ sorted, int B)
{
    cg::grid_group grid = cg::this_grid();
    const int t   = threadIdx.x;
    const int tid = blockIdx.x * COOP_BLOCK + t;

    // ---- phase 0: zero the histogram ----
    for (int i = tid; i < NBUCKETS; i += COOP_THREADS) offs[i] = 0u;
    grid.sync();

    // ---- phase B: load positions, key, histogram (keep in registers) ----
    float px[POS_PER_THREAD], py[POS_PER_THREAD], pz[POS_PER_THREAD];
    unsigned key[POS_PER_THREAD];
    #pragma unroll
    for (int j = 0; j < POS_PER_THREAD; ++j) {
        const int i = tid + j * COOP_THREADS;
        if (i < B) {
            px[j] = positions[(size_t)i * 3 + 0];
            py[j] = positions[(size_t)i * 3 + 1];
            pz[j] = positions[(size_t)i * 3 + 2];
            key[j] = morton_key(px[j], py[j], pz[j]);
            atomicAdd(&offs[key[j]], 1u);
        } else {
            key[j] = 0xFFFFFFFFu;
        }
    }
    grid.sync();

    // ---- phase C1: per-block sum + local exclusive of 32 bins ----
    __shared__ unsigned s_bins[BINS_PER_BLOCK];
    __shared__ unsigned s_ex[BINS_PER_BLOCK];
    __shared__ unsigned s_part[COOP_BLOCK];
    if (t < BINS_PER_BLOCK) s_bins[t] = offs[blockIdx.x * BINS_PER_BLOCK + t];
    __syncthreads();
    if (t == 0) {
        unsigned run = 0;
        #pragma unroll
        for (int k = 0; k < BINS_PER_BLOCK; ++k) { s_ex[k] = run; run += s_bins[k]; }
        block_sums[blockIdx.x] = run;
    }
    grid.sync();

    // ---- phase C2: block 0 exclusive-scans block_sums[COOP_GRID] ----
    if (blockIdx.x == 0) {
        unsigned v[COOP_GRID / COOP_BLOCK];  // 4
        unsigned sum = 0;
        #pragma unroll
        for (int k = 0; k < 4; ++k) { v[k] = block_sums[t * 4 + k]; sum += v[k]; }
        s_part[t] = sum;
        __syncthreads();
        for (int off = 1; off < COOP_BLOCK; off <<= 1) {
            unsigned u = (t >= off) ? s_part[t - off] : 0u;
            __syncthreads();
            s_part[t] += u;
            __syncthreads();
        }
        unsigned run = s_part[t] - sum;  // exclusive base
        #pragma unroll
        for (int k = 0; k < 4; ++k) { unsigned tmp = v[k]; block_sums[t * 4 + k] = run; run += tmp; }
    }
    grid.sync();

    // ---- phase C3: global exclusive offsets back into offs ----
    if (t < BINS_PER_BLOCK) {
        offs[blockIdx.x * BINS_PER_BLOCK + t] = block_sums[blockIdx.x] + s_ex[t];
    }
    grid.sync();

    // ---- phase D: scatter from registers ----
    #pragma unroll
    for (int j = 0; j < POS_PER_THREAD; ++j) {
        const int i = tid + j * COOP_THREADS;
        if (i < B) {
            unsigned dst = atomicAdd(&offs[key[j]], 1u);
            sorted[dst] = make_float4(px[j], py[j], pz[j], __int_as_float(i));
        }
    }
}

// ---------------- legacy passes (fallback if cooperative launch fails) ------
__global__ __launch_bounds__(256) void hist_kernel(
    const float* __restrict__ positions, unsigned* __restrict__ hist, int B)
{
    int i = blockIdx.x * blockDim.x + threadIdx.x;
    if (i >= B) return;
    const float x = positions[(size_t)i * 3 + 0];
    const float y = positions[(size_t)i * 3 + 1];
    const float z = positions[(size_t)i * 3 + 2];
    atomicAdd(&hist[morton_key(x, y, z)], 1u);
}

__global__ __launch_bounds__(SCAN_THREADS) void scan_kernel(unsigned* __restrict__ hist)
{
    __shared__ unsigned partials[SCAN_THREADS];
    const int t = threadIdx.x;
    unsigned vals[PER_THREAD];
    unsigned sum = 0;
    #pragma unroll
    for (int j = 0; j < PER_THREAD; ++j) {
        vals[j] = hist[t * PER_THREAD + j];
        sum += vals[j];
    }
    partials[t] = sum;
    __syncthreads();
    #pragma unroll
    for (int off = 1; off < SCAN_THREADS; off <<= 1) {
        unsigned u = (t >= off) ? partials[t - off] : 0u;
        __syncthreads();
        partials[t] += u;
        __syncthreads();
    }
    unsigned running = partials[t] - sum;
    #pragma unroll
    for (int j = 0; j < PER_THREAD; ++j) {
        unsigned v = vals[j];
        hist[t * PER_THREAD + j] = running;
        running += v;
    }
}

__global__ __launch_bounds__(256) void scatter_kernel(
    const float* __restrict__ positions, unsigned* __restrict__ offs,
    float4* __restrict__ sorted, int B)
{
    int i = blockIdx.x * blockDim.x + threadIdx.x;
    if (i >= B) return;
    const float x = positions[(size_t)i * 3 + 0];
    const float y = positions[(size_t)i * 3 + 1];
    const float z = positions[(size_t)i * 3 + 2];
    unsigned k = morton_key(x, y, z);
    unsigned dst = atomicAdd(&offs[k], 1u);
    sorted[dst] = make_float4(x, y, z, __int_as_float(i));
}

// ---------------- main kernel (round-0 structure + per-level load batching) -
// One thread = one position = 128B contiguous output (L2 write-back merges
// into full lines -> no write amplification, proven WRITE ~281 MB).
// Per level: 12 addresses -> 12 independent gathers -> consume.
__global__ __launch_bounds__(256) void triplane_sorted_kernel(
    const float4* __restrict__ sorted,
    const float* __restrict__ plane_embedding,
    float* __restrict__ out, int B, int swizzle)
{
    int b = blockIdx.x;
    if (swizzle) {
        // give each XCD one contiguous morton octant
        int per = gridDim.x >> 3;
        b = (b & 7) * per + (b >> 3);
    }
    int i = b * blockDim.x + threadIdx.x;
    if (i >= B) return;

    const float4 p = sorted[i];
    const int orig = __float_as_int(p.w);
    const float2* __restrict__ tab = (const float2*)plane_embedding;
    float4* __restrict__ o4 = (float4*)(out + (size_t)orig * 32);

    #pragma unroll
    for (int l = 0; l < 4; ++l) {
        const int   fac = 8 >> l;                    // 8,4,2,1
        const float s   = (float)(128 << l) - 1.0f;  // 127,255,511,1023

        const float fpx = p.x * s + 0.5f;
        const float fpy = p.y * s + 0.5f;
        const float fpz = p.z * s + 0.5f;
        const int gx = (int)floorf(fpx);
        const int gy = (int)floorf(fpy);
        const int gz = (int)floorf(fpz);
        const float fx = fpx - (float)gx;
        const float fy = fpy - (float)gy;
        const float fz = fpz - (float)gz;

        const int   g0s[3] = {gx, gy, gz};
        const int   g1s[3] = {gy, gz, gx};
        const float f0s[3] = {fx, fy, fz};
        const float f1s[3] = {fy, fz, fx};

        // phase 1: all 12 addresses
        int off[3][4];
        #pragma unroll
        for (int pl = 0; pl < 3; ++pl) {
            const int i0a = min(g0s[pl] * fac,       PLANE_RES - 1);
            const int i0b = min((g0s[pl] + 1) * fac, PLANE_RES - 1);
            const int r1a = min(g1s[pl] * fac,       PLANE_RES - 1) * PLANE_RES;
            const int r1b = min((g1s[pl] + 1) * fac, PLANE_RES - 1) * PLANE_RES;
            off[pl][0] = i0a + r1a;
            off[pl][1] = i0a + r1b;
            off[pl][2] = i0b + r1a;
            off[pl][3] = i0b + r1b;
        }

        // phase 2: 12 independent gathers
        float2 c[3][4];
        #pragma unroll
        for (int pl = 0; pl < 3; ++pl) {
            const float2* __restrict__ base = tab + (size_t)pl * PLANE_STRIDE;
            #pragma unroll
            for (int k = 0; k < 4; ++k) c[pl][k] = base[off[pl][k]];
        }

        // phase 3: consume
        float acc[3][2];
        #pragma unroll
        for (int pl = 0; pl < 3; ++pl) {
            const float w0 = f0s[pl], w1 = f1s[pl];
            const float w00 = (1.0f - w0) * (1.0f - w1);
            const float w01 = (1.0f - w0) * w1;
            const float w10 = w0 * (1.0f - w1);
            const float w11 = w0 * w1;
            acc[pl][0] = w00 * c[pl][0].x + w01 * c[pl][1].x
                       + w10 * c[pl][2].x + w11 * c[pl][3].x;
            acc[pl][1] = w00 * c[pl][0].y + w01 * c[pl][1].y
                       + w10 * c[pl][2].y + w11 * c[pl][3].y;
        }

        o4[l * 2 + 0] = make_float4(acc[0][0], acc[0][1], acc[1][0], acc[1][1]);
        o4[l * 2 + 1] = make_float4(acc[2][0], acc[2][1],
                                    acc[0][0] * acc[1][0] * acc[2][0],
                                    acc[0][1] * acc[1][1] * acc[2][1]);
    }
}

// ---------------- fallback: unsorted ---------------------------------------
__global__ __launch_bounds__(256) void triplane_plain_kernel(
    const float* __restrict__ positions,
    const float* __restrict__ plane_embedding,
    float* __restrict__ out, int B)
{
    int i = blockIdx.x * blockDim.x + threadIdx.x;
    if (i >= B) return;
    const float4 p = make_float4(positions[(size_t)i * 3 + 0],
                                 positions[(size_t)i * 3 + 1],
                                 positions[(size_t)i * 3 + 2],
                                 __int_as_float(i));
    const float2* __restrict__ tab = (const float2*)plane_embedding;
    float4* __restrict__ o4 = (float4*)(out + (size_t)i * 32);

    #pragma unroll
    for (int l = 0; l < 4; ++l) {
        const int   fac = 8 >> l;
        const float s   = (float)(128 << l) - 1.0f;
        const float fpx = p.x * s + 0.5f;
        const float fpy = p.y * s + 0.5f;
        const float fpz = p.z * s + 0.5f;
        const int gx = (int)floorf(fpx);
        const int gy = (int)floorf(fpy);
        const int gz = (int)floorf(fpz);
        const float fx = fpx - (float)gx;
        const float fy = fpy - (float)gy;
        const float fz = fpz - (float)gz;
        const int   g0s[3] = {gx, gy, gz};
        const int   g1s[3] = {gy, gz, gx};
        const float f0s[3] = {fx, fy, fz};
        const float f1s[3] = {fy, fz, fx};
        float acc[3][2];
        #pragma unroll
        for (int pl = 0; pl < 3; ++pl) {
            const int i0a = min(g0s[pl] * fac,       PLANE_RES - 1);
            const int i0b = min((g0s[pl] + 1) * fac, PLANE_RES - 1);
            const int i1a = min(g1s[pl] * fac,       PLANE_RES - 1);
            const int i1b = min((g1s[pl] + 1) * fac, PLANE_RES - 1);
            const float2* __restrict__ base = tab + (size_t)pl * PLANE_STRIDE;
            const float2 c00 = base[i0a + i1a * PLANE_RES];
            const float2 c01 = base[i0a + i1b * PLANE_RES];
            const float2 c10 = base[i0b + i1a * PLANE_RES];
            const float2 c11 = base[i0b + i1b * PLANE_RES];
            const float w0 = f0s[pl], w1 = f1s[pl];
            acc[pl][0] = (1.0f-w0)*(1.0f-w1)*c00.x + (1.0f-w0)*w1*c01.x
                       + w0*(1.0f-w1)*c10.x + w0*w1*c11.x;
            acc[pl][1] = (1.0f-w0)*(1.0f-w1)*c00.y + (1.0f-w0)*w1*c01.y
                       + w0*(1.0f-w1)*c10.y + w0*w1*c11.y;
        }
        o4[l * 2 + 0] = make_float4(acc[0][0], acc[0][1], acc[1][0], acc[1][1]);
        o4[l * 2 + 1] = make_float4(acc[2][0], acc[2][1],
                                    acc[0][0] * acc[1][0] * acc[2][0],
                                    acc[0][1] * acc[1][1] * acc[2][1]);
    }
}

extern "C" void kernel_launch(void* const* d_in, const int* in_sizes, int n_in,
                              void* d_out, int out_size, void* d_ws, size_t ws_size,
                              hipStream_t stream) {
    const float* positions = (const float*)d_in[0];
    const float* plane_embedding = (const float*)d_in[1];
    float* out = (float*)d_out;
    const int B = in_sizes[0] / 3;

    const int block = 256;
    const int grid = (B + block - 1) / block;

    // ws layout: offs[32K] | block_sums[1K] | sorted float4[B]
    const size_t offs_bytes = (size_t)NBUCKETS * sizeof(unsigned);
    const size_t bs_bytes   = (size_t)COOP_GRID * sizeof(unsigned);
    const size_t need = offs_bytes + bs_bytes + (size_t)B * sizeof(float4);

    if (ws_size < need) {
        triplane_plain_kernel<<<grid, block, 0, stream>>>(positions, plane_embedding, out, B);
        return;
    }

    unsigned* offs       = (unsigned*)d_ws;
    unsigned* block_sums = (unsigned*)((char*)d_ws + offs_bytes);
    float4*   sorted     = (float4*)((char*)d_ws + offs_bytes + bs_bytes);

    bool coop_ok = false;
    if (B <= COOP_THREADS * POS_PER_THREAD) {
        void* args[] = { (void*)&positions, (void*)&offs, (void*)&block_sums,
                         (void*)&sorted, (void*)&B };
        hipError_t e = hipLaunchCooperativeKernel(
            reinterpret_cast<void*>(sort_coop_kernel),
            dim3(COOP_GRID), dim3(COOP_BLOCK), args, 0, stream);
        coop_ok = (e == hipSuccess);
    }

    if (!coop_ok) {
        (void)hipMemsetAsync(offs, 0, offs_bytes, stream);
        hist_kernel<<<grid, block, 0, stream>>>(positions, offs, B);
        scan_kernel<<<1, SCAN_THREADS, 0, stream>>>(offs);
        scatter_kernel<<<grid, block, 0, stream>>>(positions, offs, sorted, B);
    }

    const int swizzle = (grid % 8 == 0) ? 1 : 0;
    triplane_sorted_kernel<<<grid, block, 0, stream>>>(sorted, plane_embedding, out, B, swizzle);
}

// Round 6
// 745.324 us; speedup vs baseline: 1.6609x; 1.6609x over previous
//
#include <hip/hip_runtime.h>

#define PLANE_RES 1024
#define PLANE_STRIDE (PLANE_RES * PLANE_RES)  // float2 elements per plane
#define NBUCKETS 32768                        // 2^15 morton buckets (5 bits/axis)
#define SCAN_THREADS 1024
#define PER_THREAD (NBUCKETS / SCAN_THREADS)  // 32

#if defined(__has_builtin)
#if __has_builtin(__builtin_amdgcn_sched_barrier)
#define SCHED_FENCE() __builtin_amdgcn_sched_barrier(0)
#endif
#endif
#ifndef SCHED_FENCE
#define SCHED_FENCE() ((void)0)
#endif

// ---------------- morton key: top 5 bits of each axis's level-3 cell --------
__device__ __forceinline__ unsigned part1by2(unsigned v) {
    v &= 0x3ff;
    v = (v | (v << 16)) & 0x030000FFu;
    v = (v | (v << 8))  & 0x0300F00Fu;
    v = (v | (v << 4))  & 0x030C30C3u;
    v = (v | (v << 2))  & 0x09249249u;
    return v;
}

__device__ __forceinline__ unsigned morton_key(float x, float y, float z) {
    int gx = (int)floorf(x * 1023.0f + 0.5f);
    int gy = (int)floorf(y * 1023.0f + 0.5f);
    int gz = (int)floorf(z * 1023.0f + 0.5f);
    unsigned bx = ((unsigned)gx) >> 5;  // [0,31]
    unsigned by = ((unsigned)gy) >> 5;
    unsigned bz = ((unsigned)gz) >> 5;
    return (part1by2(bx) << 2) | (part1by2(by) << 1) | part1by2(bz);  // 15 bits
}

// ---------------- pass 1: histogram ----------------------------------------
// NOTE (r3 lesson): latency-bound atomic streams want MAX thread-parallelism
// (2M threads, 1 atomic each), not per-thread batching — hipcc serializes
// per-thread batches at ~36 VGPRs.
__global__ __launch_bounds__(256) void hist_kernel(
    const float* __restrict__ positions, unsigned* __restrict__ hist, int B)
{
    int i = blockIdx.x * blockDim.x + threadIdx.x;
    if (i >= B) return;
    const float x = positions[(size_t)i * 3 + 0];
    const float y = positions[(size_t)i * 3 + 1];
    const float z = positions[(size_t)i * 3 + 2];
    atomicAdd(&hist[morton_key(x, y, z)], 1u);
}

// ---------------- pass 2: exclusive scan of 32768 bins, single block -------
__global__ __launch_bounds__(SCAN_THREADS) void scan_kernel(unsigned* __restrict__ hist)
{
    __shared__ unsigned partials[SCAN_THREADS];
    const int t = threadIdx.x;
    unsigned vals[PER_THREAD];
    unsigned sum = 0;
    #pragma unroll
    for (int j = 0; j < PER_THREAD; ++j) {
        vals[j] = hist[t * PER_THREAD + j];
        sum += vals[j];
    }
    partials[t] = sum;
    __syncthreads();
    // Hillis-Steele inclusive scan over 1024 partials
    #pragma unroll
    for (int off = 1; off < SCAN_THREADS; off <<= 1) {
        unsigned u = (t >= off) ? partials[t - off] : 0u;
        __syncthreads();
        partials[t] += u;
        __syncthreads();
    }
    unsigned running = partials[t] - sum;  // exclusive base for this thread
    #pragma unroll
    for (int j = 0; j < PER_THREAD; ++j) {
        unsigned v = vals[j];
        hist[t * PER_THREAD + j] = running;
        running += v;
    }
}

// ---------------- pass 3: scatter positions into morton order --------------
__global__ __launch_bounds__(256) void scatter_kernel(
    const float* __restrict__ positions, unsigned* __restrict__ offs,
    float4* __restrict__ sorted, int B)
{
    int i = blockIdx.x * blockDim.x + threadIdx.x;
    if (i >= B) return;
    const float x = positions[(size_t)i * 3 + 0];
    const float y = positions[(size_t)i * 3 + 1];
    const float z = positions[(size_t)i * 3 + 2];
    unsigned k = morton_key(x, y, z);
    unsigned dst = atomicAdd(&offs[k], 1u);
    sorted[dst] = make_float4(x, y, z, __int_as_float(i));
}

// ---------------- main kernel: forced-MLP, level-pair batched gathers -------
// One thread = one position = 128B contiguous plain stores (proven: no write
// amplification). Levels processed in pairs {0,1},{2,3}: 24 addresses ->
// 24 independent gathers -> sched_barrier(0) -> consume. The barrier forbids
// sinking loads past it, forcing the allocator to keep all 24 float2 results
// live (~48 data VGPRs) -> 24 outstanding loads/wave instead of ~6.
__global__ __launch_bounds__(256) void triplane_sorted_kernel(
    const float4* __restrict__ sorted,
    const float* __restrict__ plane_embedding,
    float* __restrict__ out, int B, int swizzle)
{
    int b = blockIdx.x;
    if (swizzle) {
        // give each XCD one contiguous morton octant
        int per = gridDim.x >> 3;
        b = (b & 7) * per + (b >> 3);
    }
    int i = b * blockDim.x + threadIdx.x;
    if (i >= B) return;

    const float4 p = sorted[i];
    const int orig = __float_as_int(p.w);
    const float2* __restrict__ tab = (const float2*)plane_embedding;
    float4* __restrict__ o4 = (float4*)(out + (size_t)orig * 32);

    #pragma unroll
    for (int lp = 0; lp < 2; ++lp) {
        int   off[2][3][4];
        float w0s[2][3], w1s[2][3];

        // ---- phase 1: all 24 addresses for this level pair ----
        #pragma unroll
        for (int h = 0; h < 2; ++h) {
            const int l = lp * 2 + h;
            const int   fac = 8 >> l;                    // 8,4,2,1
            const float s   = (float)(128 << l) - 1.0f;  // 127,255,511,1023

            const float fpx = p.x * s + 0.5f;
            const float fpy = p.y * s + 0.5f;
            const float fpz = p.z * s + 0.5f;
            const int gx = (int)floorf(fpx);
            const int gy = (int)floorf(fpy);
            const int gz = (int)floorf(fpz);
            const float fx = fpx - (float)gx;
            const float fy = fpy - (float)gy;
            const float fz = fpz - (float)gz;

            const int   g0s[3] = {gx, gy, gz};
            const int   g1s[3] = {gy, gz, gx};
            const float f0s[3] = {fx, fy, fz};
            const float f1s[3] = {fy, fz, fx};

            #pragma unroll
            for (int pl = 0; pl < 3; ++pl) {
                const int i0a = min(g0s[pl] * fac,       PLANE_RES - 1);
                const int i0b = min((g0s[pl] + 1) * fac, PLANE_RES - 1);
                const int r1a = min(g1s[pl] * fac,       PLANE_RES - 1) * PLANE_RES;
                const int r1b = min((g1s[pl] + 1) * fac, PLANE_RES - 1) * PLANE_RES;
                off[h][pl][0] = i0a + r1a;
                off[h][pl][1] = i0a + r1b;
                off[h][pl][2] = i0b + r1a;
                off[h][pl][3] = i0b + r1b;
                w0s[h][pl] = f0s[pl];
                w1s[h][pl] = f1s[pl];
            }
        }

        // ---- phase 2: 24 independent gathers, all issued before any use ----
        float2 c[2][3][4];
        #pragma unroll
        for (int h = 0; h < 2; ++h) {
            #pragma unroll
            for (int pl = 0; pl < 3; ++pl) {
                const float2* __restrict__ base = tab + (size_t)pl * PLANE_STRIDE;
                #pragma unroll
                for (int k = 0; k < 4; ++k) c[h][pl][k] = base[off[h][pl][k]];
            }
        }
        // nothing may cross: loads can't sink below, consumes can't hoist above
        SCHED_FENCE();

        // ---- phase 3: consume both levels, write 4 float4 (64B) ----
        #pragma unroll
        for (int h = 0; h < 2; ++h) {
            const int l = lp * 2 + h;
            float acc[3][2];
            #pragma unroll
            for (int pl = 0; pl < 3; ++pl) {
                const float w0 = w0s[h][pl], w1 = w1s[h][pl];
                const float w00 = (1.0f - w0) * (1.0f - w1);
                const float w01 = (1.0f - w0) * w1;
                const float w10 = w0 * (1.0f - w1);
                const float w11 = w0 * w1;
                acc[pl][0] = w00 * c[h][pl][0].x + w01 * c[h][pl][1].x
                           + w10 * c[h][pl][2].x + w11 * c[h][pl][3].x;
                acc[pl][1] = w00 * c[h][pl][0].y + w01 * c[h][pl][1].y
                           + w10 * c[h][pl][2].y + w11 * c[h][pl][3].y;
            }
            o4[l * 2 + 0] = make_float4(acc[0][0], acc[0][1], acc[1][0], acc[1][1]);
            o4[l * 2 + 1] = make_float4(acc[2][0], acc[2][1],
                                        acc[0][0] * acc[1][0] * acc[2][0],
                                        acc[0][1] * acc[1][1] * acc[2][1]);
        }
    }
}

// ---------------- fallback: unsorted ---------------------------------------
__global__ __launch_bounds__(256) void triplane_plain_kernel(
    const float* __restrict__ positions,
    const float* __restrict__ plane_embedding,
    float* __restrict__ out, int B)
{
    int i = blockIdx.x * blockDim.x + threadIdx.x;
    if (i >= B) return;
    const float x = positions[(size_t)i * 3 + 0];
    const float y = positions[(size_t)i * 3 + 1];
    const float z = positions[(size_t)i * 3 + 2];
    const float2* __restrict__ tab = (const float2*)plane_embedding;
    float4* __restrict__ o4 = (float4*)(out + (size_t)i * 32);

    #pragma unroll
    for (int l = 0; l < 4; ++l) {
        const int   fac = 8 >> l;
        const float s   = (float)(128 << l) - 1.0f;
        const float fpx = x * s + 0.5f;
        const float fpy = y * s + 0.5f;
        const float fpz = z * s + 0.5f;
        const int gx = (int)floorf(fpx);
        const int gy = (int)floorf(fpy);
        const int gz = (int)floorf(fpz);
        const float fx = fpx - (float)gx;
        const float fy = fpy - (float)gy;
        const float fz = fpz - (float)gz;
        const int   g0s[3] = {gx, gy, gz};
        const int   g1s[3] = {gy, gz, gx};
        const float f0s[3] = {fx, fy, fz};
        const float f1s[3] = {fy, fz, fx};
        float acc[3][2];
        #pragma unroll
        for (int pl = 0; pl < 3; ++pl) {
            const int i0a = min(g0s[pl] * fac,       PLANE_RES - 1);
            const int i0b = min((g0s[pl] + 1) * fac, PLANE_RES - 1);
            const int i1a = min(g1s[pl] * fac,       PLANE_RES - 1);
            const int i1b = min((g1s[pl] + 1) * fac, PLANE_RES - 1);
            const float2* __restrict__ base = tab + (size_t)pl * PLANE_STRIDE;
            const float2 c00 = base[i0a + i1a * PLANE_RES];
            const float2 c01 = base[i0a + i1b * PLANE_RES];
            const float2 c10 = base[i0b + i1a * PLANE_RES];
            const float2 c11 = base[i0b + i1b * PLANE_RES];
            const float w0 = f0s[pl], w1 = f1s[pl];
            acc[pl][0] = (1.0f-w0)*(1.0f-w1)*c00.x + (1.0f-w0)*w1*c01.x
                       + w0*(1.0f-w1)*c10.x + w0*w1*c11.x;
            acc[pl][1] = (1.0f-w0)*(1.0f-w1)*c00.y + (1.0f-w0)*w1*c01.y
                       + w0*(1.0f-w1)*c10.y + w0*w1*c11.y;
        }
        o4[l * 2 + 0] = make_float4(acc[0][0], acc[0][1], acc[1][0], acc[1][1]);
        o4[l * 2 + 1] = make_float4(acc[2][0], acc[2][1],
                                    acc[0][0] * acc[1][0] * acc[2][0],
                                    acc[0][1] * acc[1][1] * acc[2][1]);
    }
}

extern "C" void kernel_launch(void* const* d_in, const int* in_sizes, int n_in,
                              void* d_out, int out_size, void* d_ws, size_t ws_size,
                              hipStream_t stream) {
    const float* positions = (const float*)d_in[0];
    const float* plane_embedding = (const float*)d_in[1];
    float* out = (float*)d_out;
    const int B = in_sizes[0] / 3;

    const int block = 256;
    const int grid = (B + block - 1) / block;

    // ws layout: [0, 128KB) offsets/hist, [128KB, 128KB + B*16) sorted float4
    const size_t offs_bytes = (size_t)NBUCKETS * sizeof(unsigned);
    const size_t need = offs_bytes + (size_t)B * sizeof(float4);

    if (ws_size < need) {
        triplane_plain_kernel<<<grid, block, 0, stream>>>(positions, plane_embedding, out, B);
        return;
    }

    unsigned* offs = (unsigned*)d_ws;
    float4* sorted = (float4*)((char*)d_ws + offs_bytes);

    (void)hipMemsetAsync(offs, 0, offs_bytes, stream);
    hist_kernel<<<grid, block, 0, stream>>>(positions, offs, B);
    scan_kernel<<<1, SCAN_THREADS, 0, stream>>>(offs);
    scatter_kernel<<<grid, block, 0, stream>>>(positions, offs, sorted, B);

    const int swizzle = (grid % 8 == 0) ? 1 : 0;
    triplane_sorted_kernel<<<grid, block, 0, stream>>>(sorted, plane_embedding, out, B, swizzle);
}